// Round 11
// baseline (770.020 us; speedup 1.0000x reference)
//
#include <hip/hip_runtime.h>
#include <hip/hip_bf16.h>

// MHA layer: B=2 S=2048 D=1024 H=16 HD=64. fp32 accum, bf16 MFMA internally.
// SINGLE persistent kernel, 512 blocks x 256 thr (co-residency guaranteed:
// LDS 34.8KB -> 4/CU possible, launch_bounds(256,2), grid = 2x256).
// Software grid barriers (device-scope atomics in d_ws, memset to 0 per
// launch). Phases (bodies identical to r10's verified kernels):
//   P0 W transpose -> P1 fused QKV GEMM -> P2 flash attention -> P3 out GEMM.

#define S_ 2048
#define D_ 1024
#define HD_ 64
#define LDSW 72      // padded LDS row stride (shorts) for Ps/Ts
#define QSZ 4194304  // shorts per Q/K/V buffer (32*2048*64)
#define LOG2E 1.44269504f
#define NBLK 512

typedef __attribute__((ext_vector_type(8))) short bf16x8;
typedef __attribute__((ext_vector_type(4))) float f32x4;

static __device__ __forceinline__ short f2bs(float f) {
    __hip_bfloat16 h = __float2bfloat16(f);
    return *reinterpret_cast<short*>(&h);
}
static __device__ __forceinline__ float bs2f(short s) {
    __hip_bfloat16 h = *reinterpret_cast<__hip_bfloat16*>(&s);
    return __bfloat162float(h);
}
static __device__ __forceinline__ bf16x8 cvt8(const float* p) {
    f32x4 u0 = *(const f32x4*)p;
    f32x4 u1 = *(const f32x4*)(p + 4);
    bf16x8 r;
    r[0] = f2bs(u0[0]); r[1] = f2bs(u0[1]); r[2] = f2bs(u0[2]); r[3] = f2bs(u0[3]);
    r[4] = f2bs(u1[0]); r[5] = f2bs(u1[1]); r[6] = f2bs(u1[2]); r[7] = f2bs(u1[3]);
    return r;
}
static __device__ __forceinline__ void gld16(const void* g, void* l) {
    __builtin_amdgcn_global_load_lds(
        (const __attribute__((address_space(1))) unsigned int*)g,
        (__attribute__((address_space(3))) unsigned int*)l, 16, 0, 0);
}
static __device__ __forceinline__ int detect_f32(const unsigned int* __restrict__ xw) {
    const unsigned int w = xw[threadIdx.x & 63];
    const int e = (int)((w >> 7) & 0xFFu);
    unsigned long long m = __ballot(e >= 117 && e <= 130);
    return (__popcll(m) >= 32) ? 0 : 1;
}
// software grid barrier: all NBLK blocks co-resident by construction.
static __device__ __forceinline__ void gsync(int* c, int target) {
    __threadfence();                 // release: drain all global writes
    __syncthreads();
    if (threadIdx.x == 0) {
        __hip_atomic_fetch_add(c, 1, __ATOMIC_ACQ_REL, __HIP_MEMORY_SCOPE_AGENT);
        while (__hip_atomic_load(c, __ATOMIC_ACQUIRE, __HIP_MEMORY_SCOPE_AGENT) < target)
            __builtin_amdgcn_s_sleep(2);
    }
    __syncthreads();
    __threadfence();                 // acquire
}

// Shared-memory union across phases (34816 B max)
union SMemU {
    struct { short As[128 * 64]; short Bs[128 * 64]; } g;                       // 32 KB
    struct { short Ts[64 * LDSW]; } t;                                          // 9 KB
    struct { short Ks[64 * 64]; short Vs[64 * 64]; short Ps[4][32 * LDSW]; } a; // 34 KB
};

// ---------------------------------------------------------------------------
__global__ __launch_bounds__(256, 2) void fused_mha(
    const void* __restrict__ x,
    const void* __restrict__ wq, const void* __restrict__ wk,
    const void* __restrict__ wv, const void* __restrict__ wo,
    const void* __restrict__ bq, const void* __restrict__ bk,
    const void* __restrict__ bv, const void* __restrict__ bo,
    void* __restrict__ Cout,
    short* __restrict__ Wt, short* __restrict__ Att, short* __restrict__ QKV,
    int* __restrict__ ctr)
{
    __shared__ __align__(16) SMemU sm;

    const int bid = blockIdx.x;
    const int t = threadIdx.x;
    const int wave = t >> 6, lane = t & 63;
    const int quad = lane >> 4, l16 = lane & 15;
    const int lr = lane >> 3;
    const int kx = ((lane & 7) ^ (lr & 7)) * 8;
    const int ext_f32 = detect_f32((const unsigned int*)x);

    // ================= P0: W transpose (1024 tiles) ======================
    {
        const int row = t >> 2, seg = t & 3;
        for (int T = bid; T < 1024; T += NBLK) {
            const int z = T >> 8, bb = T & 255;
            const void* W = z == 0 ? wq : z == 1 ? wk : z == 2 ? wv : wo;
            short* O = Wt + (size_t)z * D_ * D_;
            const int k0 = (bb & 15) * 64, n0 = (bb >> 4) * 64;
            __syncthreads();
            if (ext_f32) {
                const float* wg = (const float*)W + (size_t)(k0 + row) * D_ + n0;
                *(bf16x8*)&sm.t.Ts[row * LDSW + seg * 8]      = cvt8(wg + seg * 8);
                *(bf16x8*)&sm.t.Ts[row * LDSW + seg * 8 + 32] = cvt8(wg + seg * 8 + 32);
            } else {
                const short* wg = (const short*)W + (size_t)(k0 + row) * D_ + n0;
                *(bf16x8*)&sm.t.Ts[row * LDSW + seg * 8]      = *(const bf16x8*)(wg + seg * 8);
                *(bf16x8*)&sm.t.Ts[row * LDSW + seg * 8 + 32] = *(const bf16x8*)(wg + seg * 8 + 32);
            }
            __syncthreads();
            short* og = O + (size_t)(n0 + row) * D_ + k0;
            #pragma unroll
            for (int g = 0; g < 2; ++g) {
                const int ks = seg * 8 + g * 32;
                alignas(16) short tmp[8];
                #pragma unroll
                for (int i = 0; i < 8; ++i) tmp[i] = sm.t.Ts[(ks + i) * LDSW + row];
                *(bf16x8*)(og + ks) = *(const bf16x8*)tmp;
            }
        }
    }
    gsync(ctr + 0, NBLK);

    // ================= P1: fused QKV GEMM (768 tiles) ====================
    for (int T = bid; T < 768; T += NBLK) {
        const int m0 = (T & 31) * 128, n0 = (T >> 5) * 128;
        const int id = n0 >> 10;
        const int wm = wave & 1, wn = wave >> 1;

        f32x4 acc[4][4];
        #pragma unroll
        for (int i = 0; i < 4; ++i)
            #pragma unroll
            for (int j = 0; j < 4; ++j) acc[i][j] = (f32x4){0.f, 0.f, 0.f, 0.f};

        const size_t arow = (size_t)(m0 + wave * 32 + lr) * D_ + kx;
        const short* Bb = Wt + (size_t)(n0 + wave * 32 + lr) * D_ + kx;

        for (int kb = 0; kb < 16; ++kb) {
            __syncthreads();
            const int k0 = kb * 64;
            if (ext_f32) {
                const float* Xf = (const float*)x;
                #pragma unroll
                for (int i = 0; i < 4; ++i)
                    *(bf16x8*)&sm.g.As[(wave * 4 + i) * 512 + lane * 8] =
                        cvt8(Xf + arow + (size_t)i * 8 * D_ + k0);
            } else {
                const short* Xs = (const short*)x;
                #pragma unroll
                for (int i = 0; i < 4; ++i)
                    gld16(Xs + arow + (size_t)i * 8 * D_ + k0, &sm.g.As[(wave * 4 + i) * 512]);
            }
            #pragma unroll
            for (int i = 0; i < 4; ++i)
                gld16(Bb + (size_t)i * 8 * D_ + k0, &sm.g.Bs[(wave * 4 + i) * 512]);
            __syncthreads();

            #pragma unroll
            for (int ks = 0; ks < 2; ++ks) {
                const int sw = ((ks * 4 + quad) ^ (l16 & 7)) * 8;
                bf16x8 af[4], bfr[4];
                #pragma unroll
                for (int i = 0; i < 4; ++i) {
                    af[i]  = *(const bf16x8*)&sm.g.As[(wm * 64 + i * 16 + l16) * 64 + sw];
                    bfr[i] = *(const bf16x8*)&sm.g.Bs[(wn * 64 + i * 16 + l16) * 64 + sw];
                }
                #pragma unroll
                for (int mi = 0; mi < 4; ++mi)
                    #pragma unroll
                    for (int ni = 0; ni < 4; ++ni)
                        acc[mi][ni] = __builtin_amdgcn_mfma_f32_16x16x32_bf16(
                            af[mi], bfr[ni], acc[mi][ni], 0, 0, 0);
            }
        }

        const void* bias = id == 0 ? bq : id == 1 ? bk : bv;
        const float oscale = id == 0 ? 0.125f : 1.0f;
        #pragma unroll
        for (int ni = 0; ni < 4; ++ni) {
            const int n = n0 + wn * 64 + ni * 16 + l16;
            const int nl = n & 1023, h = nl >> 6, d = nl & 63;
            const float bvl = ext_f32 ? ((const float*)bias)[nl]
                                      : bs2f(((const short*)bias)[nl]);
            #pragma unroll
            for (int mi = 0; mi < 4; ++mi)
                #pragma unroll
                for (int r = 0; r < 4; ++r) {
                    const int m = m0 + wm * 64 + mi * 16 + quad * 4 + r;
                    const int b = m >> 11, s = m & 2047;
                    const int bh = b * 16 + h;
                    const float v = (acc[mi][ni][r] + bvl) * oscale;
                    const size_t idx = (id < 2)
                        ? (size_t)id * QSZ + ((size_t)bh * S_ + s) * HD_ + d
                        : (size_t)2 * QSZ + ((size_t)bh * HD_ + d) * S_ + s;
                    QKV[idx] = f2bs(v);
                }
        }
    }
    gsync(ctr + 1, NBLK);

    // ================= P2: flash attention (512 tiles) ===================
    {
        const short* Q  = QKV;
        const short* K  = QKV + QSZ;
        const short* Vt = QKV + 2 * QSZ;
        const int bh = bid & 31;
        const int q0 = (bid >> 5) * 128;
        short* pw = &sm.a.Ps[wave][0];

        bf16x8 bqf[2][2];
        #pragma unroll
        for (int mi = 0; mi < 2; ++mi) {
            const short* qr = Q + ((size_t)bh * S_ + q0 + wave * 32 + mi * 16 + l16) * HD_ + quad * 8;
            bqf[mi][0] = *(const bf16x8*)qr;
            bqf[mi][1] = *(const bf16x8*)(qr + 32);
        }

        bf16x8 ones;
        #pragma unroll
        for (int i = 0; i < 8; ++i) ones[i] = (short)0x3F80;

        f32x4 o[2][4], lacc[2];
        #pragma unroll
        for (int mi = 0; mi < 2; ++mi) {
            lacc[mi] = (f32x4){0.f, 0.f, 0.f, 0.f};
            #pragma unroll
            for (int nt = 0; nt < 4; ++nt) o[mi][nt] = (f32x4){0.f, 0.f, 0.f, 0.f};
        }

        const short* Kb = K  + ((size_t)bh * S_  + wave * 16 + lr) * HD_ + kx;
        const short* Vb = Vt + ((size_t)bh * HD_ + wave * 16 + lr) * S_ + kx;

        for (int j = 0; j < 32; ++j) {
            __syncthreads();
            #pragma unroll
            for (int i = 0; i < 2; ++i) {
                gld16(Kb + ((size_t)j * 64 + i * 8) * HD_, &sm.a.Ks[(wave * 2 + i) * 512]);
                gld16(Vb + (size_t)i * 8 * S_ + j * 64,    &sm.a.Vs[(wave * 2 + i) * 512]);
            }
            __syncthreads();

            f32x4 st[2][4];
            #pragma unroll
            for (int nt = 0; nt < 4; ++nt) {
                bf16x8 kf0 = *(const bf16x8*)&sm.a.Ks[(nt * 16 + l16) * 64 + ((quad ^ (l16 & 7)) * 8)];
                bf16x8 kf1 = *(const bf16x8*)&sm.a.Ks[(nt * 16 + l16) * 64 + (((4 + quad) ^ (l16 & 7)) * 8)];
                #pragma unroll
                for (int mi = 0; mi < 2; ++mi) {
                    f32x4 z = (f32x4){0.f, 0.f, 0.f, 0.f};
                    z = __builtin_amdgcn_mfma_f32_16x16x32_bf16(kf0, bqf[mi][0], z, 0, 0, 0);
                    z = __builtin_amdgcn_mfma_f32_16x16x32_bf16(kf1, bqf[mi][1], z, 0, 0, 0);
                    st[mi][nt] = z;
                }
            }

            #pragma unroll
            for (int mi = 0; mi < 2; ++mi)
                #pragma unroll
                for (int nt = 0; nt < 4; ++nt) {
                    unsigned u0 = __float_as_uint(__builtin_amdgcn_exp2f(st[mi][nt][0] * LOG2E));
                    unsigned u1 = __float_as_uint(__builtin_amdgcn_exp2f(st[mi][nt][1] * LOG2E));
                    unsigned u2 = __float_as_uint(__builtin_amdgcn_exp2f(st[mi][nt][2] * LOG2E));
                    unsigned u3 = __float_as_uint(__builtin_amdgcn_exp2f(st[mi][nt][3] * LOG2E));
                    uint2 pk;
                    pk.x = __builtin_amdgcn_perm(u1, u0, 0x07060302);
                    pk.y = __builtin_amdgcn_perm(u3, u2, 0x07060302);
                    *(uint2*)&pw[(mi * 16 + l16) * LDSW + nt * 16 + quad * 4] = pk;
                }
            __builtin_amdgcn_s_waitcnt(0xc07f);  // lgkmcnt(0): Ps wave-private

            #pragma unroll
            for (int ks = 0; ks < 2; ++ks) {
                bf16x8 vf[4];
                #pragma unroll
                for (int nt = 0; nt < 4; ++nt)
                    vf[nt] = *(const bf16x8*)&sm.a.Vs[(nt * 16 + l16) * 64 + (((ks * 4 + quad) ^ (l16 & 7)) * 8)];
                #pragma unroll
                for (int mi = 0; mi < 2; ++mi) {
                    bf16x8 ap = *(const bf16x8*)&pw[(mi * 16 + l16) * LDSW + ks * 32 + quad * 8];
                    lacc[mi] = __builtin_amdgcn_mfma_f32_16x16x32_bf16(ap, ones, lacc[mi], 0, 0, 0);
                    #pragma unroll
                    for (int nt = 0; nt < 4; ++nt)
                        o[mi][nt] = __builtin_amdgcn_mfma_f32_16x16x32_bf16(ap, vf[nt], o[mi][nt], 0, 0, 0);
                }
            }
        }

        const int b = bh >> 4, h = bh & 15;
        #pragma unroll
        for (int mi = 0; mi < 2; ++mi)
            #pragma unroll
            for (int r = 0; r < 4; ++r) {
                const float inv = 1.f / lacc[mi][r];
                const int s = q0 + wave * 32 + mi * 16 + quad * 4 + r;
                const size_t base = ((size_t)b * S_ + s) * D_ + h * HD_;
                #pragma unroll
                for (int nt = 0; nt < 4; ++nt)
                    Att[base + nt * 16 + l16] = f2bs(o[mi][nt][r] * inv);
            }
    }
    gsync(ctr + 2, NBLK);

    // ================= P3: output GEMM (512 tiles) =======================
    {
        const short* Bt = Wt + (3 << 20);     // Wo^T
        const int m0 = (bid & 63) * 64, n0 = (bid >> 6) * 128;
        const int wm = wave & 1, wn = wave >> 1;

        f32x4 acc[2][4];
        #pragma unroll
        for (int i = 0; i < 2; ++i)
            #pragma unroll
            for (int j = 0; j < 4; ++j) acc[i][j] = (f32x4){0.f, 0.f, 0.f, 0.f};

        const short* Ab = Att + (size_t)(m0 + wave * 16 + lr) * D_ + kx;
        const short* Bb = Bt  + (size_t)(n0 + wave * 32 + lr) * D_ + kx;

        for (int kb = 0; kb < 16; ++kb) {
            __syncthreads();
            const int k0 = kb * 64;
            #pragma unroll
            for (int i = 0; i < 2; ++i)
                gld16(Ab + (size_t)i * 8 * D_ + k0, &sm.g.As[(wave * 2 + i) * 512]);
            #pragma unroll
            for (int i = 0; i < 4; ++i)
                gld16(Bb + (size_t)i * 8 * D_ + k0, &sm.g.Bs[(wave * 4 + i) * 512]);
            __syncthreads();

            #pragma unroll
            for (int ks = 0; ks < 2; ++ks) {
                const int sw = ((ks * 4 + quad) ^ (l16 & 7)) * 8;
                bf16x8 af[2], bfr[4];
                #pragma unroll
                for (int i = 0; i < 2; ++i)
                    af[i] = *(const bf16x8*)&sm.g.As[(wm * 32 + i * 16 + l16) * 64 + sw];
                #pragma unroll
                for (int i = 0; i < 4; ++i)
                    bfr[i] = *(const bf16x8*)&sm.g.Bs[(wn * 64 + i * 16 + l16) * 64 + sw];
                #pragma unroll
                for (int mi = 0; mi < 2; ++mi)
                    #pragma unroll
                    for (int ni = 0; ni < 4; ++ni)
                        acc[mi][ni] = __builtin_amdgcn_mfma_f32_16x16x32_bf16(
                            af[mi], bfr[ni], acc[mi][ni], 0, 0, 0);
            }
        }

        #pragma unroll
        for (int ni = 0; ni < 4; ++ni) {
            const int n = n0 + wn * 64 + ni * 16 + l16;
            const float bvl = ext_f32 ? ((const float*)bo)[n]
                                      : bs2f(((const short*)bo)[n]);
            #pragma unroll
            for (int mi = 0; mi < 2; ++mi)
                #pragma unroll
                for (int r = 0; r < 4; ++r) {
                    const int m = m0 + wm * 32 + mi * 16 + quad * 4 + r;
                    const float v = acc[mi][ni][r] + bvl;
                    const size_t idx = (size_t)m * D_ + n;
                    if (ext_f32) ((float*)Cout)[idx] = v;
                    else         ((short*)Cout)[idx] = f2bs(v);
                }
        }
    }
}

// ---------------------------------------------------------------------------
extern "C" void kernel_launch(void* const* d_in, const int* in_sizes, int n_in,
                              void* d_out, int out_size, void* d_ws, size_t ws_size,
                              hipStream_t stream) {
    char* ws = (char*)d_ws;
    int*   ctr = (int*)ws;                               // 3 barrier counters @0
    short* Wt  = (short*)(ws + ((size_t)1  << 20));      // 4x[1024][1024] bf16, 8MB
    short* Att = (short*)(ws + ((size_t)9  << 20));      // [4096][1024] bf16, 8MB
    short* QKV = (short*)(ws + ((size_t)17 << 20));      // Q|K|Vt, 24MB

    hipMemsetAsync(ctr, 0, 64, stream);                  // zero barrier counters
    fused_mha<<<NBLK, 256, 0, stream>>>(
        d_in[0], d_in[1], d_in[3], d_in[5], d_in[7],
        d_in[2], d_in[4], d_in[6], d_in[8],
        d_out, Wt, Att, QKV, ctr);
}